// Round 12
// baseline (185.673 us; speedup 1.0000x reference)
//
#include <hip/hip_runtime.h>

// MoE: out[b,:] = sum_e softmax(gate(x))[b,e] * (W3_e^T @ relu(W2_e^T @ relu(W1_e^T @ x_b + b1) + b2) + b3)
// Tokens-as-N MFMA, 16x16 shapes (R8 math, HW-verified absmax 0.0156). L1: 16x16x16 (K=7
// useful, k=4q+j). L2/L3/gate-L2: 16x16x32 with K-permutation pi so C/D layout == next
// layer's B layout in-lane.
// R12: SINGLE-DISPATCH SPLIT-EXPERT + ATOMIC COMBINE. R11 showed two serial dispatches pay
//     2x ramp/tail and 8-tile prologue amortization (~1/3 of busy cycles). Now even blocks
//     run experts 0-3, odd blocks 4-7 (gate computed by both: 2x duplication vs R8's 4x),
//     both atomicAdd their gated partials onto memset-zeroed out. No LDS, no barriers, no
//     workspace dependency, one dispatch, 16 tiles/wave amortization, XCD-balanced split.

typedef _Float16 half2_t __attribute__((ext_vector_type(2)));
typedef _Float16 half4_t __attribute__((ext_vector_type(4)));
typedef _Float16 half8_t __attribute__((ext_vector_type(8)));
typedef __fp16   fp16v2  __attribute__((ext_vector_type(2)));
typedef float  float4_t __attribute__((ext_vector_type(4)));
typedef float  float2_t __attribute__((ext_vector_type(2)));
typedef int    int2_t   __attribute__((ext_vector_type(2)));
typedef int    int4_t   __attribute__((ext_vector_type(4)));

#define MFMA_K32(A, B, C) __builtin_amdgcn_mfma_f32_16x16x32_f16((A), (B), (C), 0, 0, 0)
#define MFMA_K16(A, B, C) __builtin_amdgcn_mfma_f32_16x16x16f16((A), (B), (C), 0, 0, 0)

static constexpr int E_ = 8, DIN_ = 6, H_ = 32, EPH_ = 4;   // experts per half

union H8U { half2_t h2[4]; half8_t h8; int4_t i4; };
union H4U { half2_t h2[2]; half4_t h4; int2_t i2; };
union HI  { half2_t h; int i; };
union PKU { fp16v2 p; half2_t h; };

__device__ __forceinline__ half2_t pkrtz(float a, float b) {
    PKU u; u.p = __builtin_amdgcn_cvt_pkrtz(a, b);
    return u.h;
}

__device__ __forceinline__ half2_t relu2(half2_t v) {
    const half2_t z = {(_Float16)0.0f, (_Float16)0.0f};
    return __builtin_elementwise_max(v, z);
}

__global__ __launch_bounds__(256)
void moe_kernel(
    const float* __restrict__ x,  const float* __restrict__ W1, const float* __restrict__ b1,
    const float* __restrict__ W2, const float* __restrict__ b2, const float* __restrict__ W3,
    const float* __restrict__ b3, const float* __restrict__ Wg1, const float* __restrict__ bg1,
    const float* __restrict__ Wg2, const float* __restrict__ bg2,
    float* __restrict__ out, int nTiles, int tilesPerWave)
{
    const int tid  = threadIdx.x;
    const int lane = tid & 63;
    const int t    = lane & 15;   // token slot (A-row m == B-col n)
    const int q    = lane >> 4;   // K-quad
    const int half_= blockIdx.x & 1;                 // 0: experts 0-3, 1: experts 4-7
    const int wid  = (int)(((blockIdx.x >> 1) * blockDim.x + tid) >> 6);  // stream id
    const int eb   = half_ * EPH_;

    const float L2E = 1.44269504f;

    // ---- gate fragments (both halves compute the gate: 2x duplication, zero dependency)
    H4U G1[2];
    H8U G2;
    #pragma unroll
    for (int f = 0; f < 2; ++f) {
        float v0 = 0.f, v1 = 0.f, v2 = 0.f, v3 = 0.f;
        if (q == 0) {
            v0 = Wg1[0 * H_ + f * 16 + t]; v1 = Wg1[1 * H_ + f * 16 + t];
            v2 = Wg1[2 * H_ + f * 16 + t]; v3 = Wg1[3 * H_ + f * 16 + t];
        } else if (q == 1) {
            v0 = Wg1[4 * H_ + f * 16 + t]; v1 = Wg1[5 * H_ + f * 16 + t];
            v2 = bg1[f * 16 + t];          v3 = 0.f;
        }
        G1[f].h2[0] = pkrtz(v0, v1); G1[f].h2[1] = pkrtz(v2, v3);
    }
    #pragma unroll
    for (int p = 0; p < 4; ++p) {
        int c0 = ((p >> 1) << 4) + q * 4 + ((p & 1) << 1);
        float v0 = (t < E_) ? Wg2[c0 * E_ + t] * L2E : 0.f;
        float v1 = (t < E_) ? Wg2[(c0 + 1) * E_ + t] * L2E : 0.f;
        G2.h2[p] = pkrtz(v0, v1);
    }

    // ---- this half's 4 experts: L1 (K16), L2 (K32 pi), L3 (K32 pi, block-diag), b2 pairs
    H4U W1F[EPH_][2];
    H8U W2F[EPH_][2], W3F[EPH_], B2R[EPH_];
    #pragma unroll
    for (int j = 0; j < EPH_; ++j) {
        const int e = eb + j;
        #pragma unroll
        for (int f = 0; f < 2; ++f) {
            float v0 = 0.f, v1 = 0.f, v2 = 0.f, v3 = 0.f;
            const float* We = W1 + (size_t)e * DIN_ * H_ + f * 16 + t;
            if (q == 0)      { v0 = We[0 * H_]; v1 = We[1 * H_]; v2 = We[2 * H_]; v3 = We[3 * H_]; }
            else if (q == 1) { v0 = We[4 * H_]; v1 = We[5 * H_]; v2 = b1[e * H_ + f * 16 + t]; }
            W1F[j][f].h2[0] = pkrtz(v0, v1); W1F[j][f].h2[1] = pkrtz(v2, v3);
        }
        #pragma unroll
        for (int p = 0; p < 4; ++p) {
            int c0 = ((p >> 1) << 4) + q * 4 + ((p & 1) << 1);
            W2F[j][0].h2[p] = pkrtz(W2[(e * H_ + c0) * H_ + 0  + t], W2[(e * H_ + c0 + 1) * H_ + 0  + t]);
            W2F[j][1].h2[p] = pkrtz(W2[(e * H_ + c0) * H_ + 16 + t], W2[(e * H_ + c0 + 1) * H_ + 16 + t]);
            B2R[j].h2[p]    = pkrtz(b2[e * H_ + c0], b2[e * H_ + c0 + 1]);
            float v0 = 0.f, v1 = 0.f;
            if ((t >> 1) == e) {               // W3 rows m=2e+o live at t=2e,2e+1
                v0 = W3[(e * H_ + c0) * 2 + (t & 1)];
                v1 = W3[(e * H_ + c0 + 1) * 2 + (t & 1)];
            }
            W3F[j].h2[p] = pkrtz(v0, v1);
        }
    }

    // ---- C-inits: bg2 (log2 domain); b3 only on this half's quads (others must stay 0)
    float4_t bg2F, b3F;
    #pragma unroll
    for (int r = 0; r < 4; ++r) {
        int m = q * 4 + r;
        bg2F[r] = (m < E_) ? bg2[m] * L2E : 0.f;
        b3F[r]  = ((q >> 1) == half_) ? b3[m] : 0.f;
    }
    const float4_t zero4 = {0.f, 0.f, 0.f, 0.f};

    // gate distribute: lane(q,t) pulls pair q (pa/pb of source lane (q>>1)*16+t)
    const int gsrc = ((((q >> 1) << 4) | t) << 2);

    const int tile0 = wid * tilesPerWave;

    // per-lane x source offsets (quads>=2 values never consumed: L1 A-frags zero at k>=8)
    const int xo1 = (q == 0) ? 0 : 4;
    const int xo2 = (q == 0) ? 2 : 4;
    const float* xq = x + ((size_t)tile0 * 16 + t) * DIN_;
    const int strideT = 16 * DIN_;

    float2_t la = {0.f, 0.f}, lb = {0.f, 0.f};
    if (tile0 < nTiles) {
        la = *(const float2_t*)(xq + xo1);
        lb = *(const float2_t*)(xq + xo2);
    }

    HI onei; onei.h = pkrtz(1.f, 0.f);
    const bool isq0 = (q == 0);

    // atomic write slot: lanes 0-15 add out[tok*2], lanes 16-31 add out[tok*2+1]
    const int osel = (lane >> 4) & 1;

    for (int it = 0; it < tilesPerWave; ++it) {
        const int tile = tile0 + it;
        if (tile >= nTiles) break;
        const int tok = tile * 16 + t;

        // ---- x B-fragment (K=16): q0:(x0..x3) q1:(x4,x5,1,dc) q2/q3: dc (A zero there)
        H4U ux;
        ux.h2[0] = pkrtz(la[0], la[1]);
        HI hb; hb.h = pkrtz(lb[0], lb[1]);
        HI se; se.i = isq0 ? hb.i : onei.i;
        ux.h2[1] = se.h;
        const half4_t xB = ux.h4;

        // ---- prefetch next tile's x
        if ((it + 1) < tilesPerWave && (tile + 1) < nTiles) {
            const float* xn = xq + (size_t)(it + 1) * strideT;
            la = *(const float2_t*)(xn + xo1);
            lb = *(const float2_t*)(xn + xo2);
        }

        // ---- gate (once per tile per half)
        float4_t hgLo = MFMA_K16(G1[0].h4, xB, zero4);
        float4_t hgHi = MFMA_K16(G1[1].h4, xB, zero4);
        H8U uh;
        uh.h2[0] = relu2(pkrtz(hgLo[0], hgLo[1]));
        uh.h2[1] = relu2(pkrtz(hgLo[2], hgLo[3]));
        uh.h2[2] = relu2(pkrtz(hgHi[0], hgHi[1]));
        uh.h2[3] = relu2(pkrtz(hgHi[2], hgHi[3]));
        float4_t gl = MFMA_K32(G2.h8, uh.h8, bg2F);

        // ---- softmax (no max-sub; logits bounded, log2e pre-folded), normalized
        float ex0 = __builtin_amdgcn_exp2f(gl[0]);
        float ex1 = __builtin_amdgcn_exp2f(gl[1]);
        float ex2 = __builtin_amdgcn_exp2f(gl[2]);
        float ex3 = __builtin_amdgcn_exp2f(gl[3]);
        float s = (ex0 + ex1) + (ex2 + ex3);
        s += __shfl_xor(s, 16);
        float rs = __builtin_amdgcn_rcpf(s);
        HI pa, pb;
        pa.h = pkrtz(ex0 * rs, ex1 * rs);   // q0: pair0(e0,e1) | q1: pair2(e4,e5)
        pb.h = pkrtz(ex2 * rs, ex3 * rs);   // q0: pair1(e2,e3) | q1: pair3(e6,e7)
        int va = __builtin_amdgcn_ds_bpermute(gsrc, pa.i);
        int vb = __builtin_amdgcn_ds_bpermute(gsrc, pb.i);
        HI gsel; gsel.i = (q & 1) ? vb : va;   // lane(q,t): g[t,2q], g[t,2q+1]
        float ga = (float)gsel.h[0];
        float gb = (float)gsel.h[1];

        // ---- 4 experts (shared Y accumulator carries this half's b3 rows)
        float4_t Y = b3F;
        #pragma unroll
        for (int j = 0; j < EPH_; ++j) {
            float4_t lo = MFMA_K16(W1F[j][0].h4, xB, zero4);
            float4_t hi = MFMA_K16(W1F[j][1].h4, xB, zero4);
            H8U u1;
            u1.h2[0] = relu2(pkrtz(lo[0], lo[1]));
            u1.h2[1] = relu2(pkrtz(lo[2], lo[3]));
            u1.h2[2] = relu2(pkrtz(hi[0], hi[1]));
            u1.h2[3] = relu2(pkrtz(hi[2], hi[3]));
            float4_t lo2 = MFMA_K32(W2F[j][0].h8, u1.h8, zero4);
            float4_t hi2 = MFMA_K32(W2F[j][1].h8, u1.h8, zero4);
            H8U u2;
            u2.h2[0] = relu2(pkrtz(lo2[0], lo2[1]) + B2R[j].h2[0]);
            u2.h2[1] = relu2(pkrtz(lo2[2], lo2[3]) + B2R[j].h2[1]);
            u2.h2[2] = relu2(pkrtz(hi2[0], hi2[1]) + B2R[j].h2[2]);
            u2.h2[3] = relu2(pkrtz(hi2[2], hi2[3]) + B2R[j].h2[3]);
            Y = MFMA_K32(W3F[j].h8, u2.h8, Y);
        }

        // ---- gated partial: rows outside this half's quads are zero; g matches rows in-quad
        float p0 = ga * Y[0] + gb * Y[2];
        float p1 = ga * Y[1] + gb * Y[3];
        p0 += __shfl_xor(p0, 16);
        p0 += __shfl_xor(p0, 32);
        p1 += __shfl_xor(p1, 16);
        p1 += __shfl_xor(p1, 32);

        // ---- combine across halves via atomics (commutative: deterministic for 2 addends)
        if (lane < 32) {
            atomicAdd(out + (size_t)tok * 2 + osel, osel ? p1 : p0);
        }
    }
}

extern "C" void kernel_launch(void* const* d_in, const int* in_sizes, int n_in,
                              void* d_out, int out_size, void* d_ws, size_t ws_size,
                              hipStream_t stream) {
    const float* x   = (const float*)d_in[0];
    const float* W1  = (const float*)d_in[1];
    const float* b1  = (const float*)d_in[2];
    const float* W2  = (const float*)d_in[3];
    const float* b2  = (const float*)d_in[4];
    const float* W3  = (const float*)d_in[5];
    const float* b3  = (const float*)d_in[6];
    const float* Wg1 = (const float*)d_in[7];
    const float* bg1 = (const float*)d_in[8];
    const float* Wg2 = (const float*)d_in[9];
    const float* bg2 = (const float*)d_in[10];
    float* out = (float*)d_out;

    const int B      = in_sizes[0] / DIN_;
    const int nTiles = (B + 15) / 16;
    const int blocks = 2048;                 // 1024 blocks/half; 4096 wave-streams/half
    const int nWavesH = (blocks / 2) * (256 / 64);
    const int tpw    = (nTiles + nWavesH - 1) / nWavesH;   // 16 tiles/wave

    hipMemsetAsync(out, 0, (size_t)out_size * sizeof(float), stream);
    moe_kernel<<<blocks, 256, 0, stream>>>(x, W1, b1, W2, b2, W3, b3,
                                           Wg1, bg1, Wg2, bg2, out, nTiles, tpw);
}

// Round 13
// 162.187 us; speedup vs baseline: 1.1448x; 1.1448x over previous
//
#include <hip/hip_runtime.h>

// MoE: out[b,:] = sum_e softmax(gate(x))[b,e] * (W3_e^T @ relu(W2_e^T @ relu(W1_e^T @ x_b + b1) + b2) + b3)
// Tokens-as-N MFMA, 16x16 shapes. L1: 16x16x16 (K=7 useful, k=4q+j). L2/L3/gate-L2: 16x16x32
// with K-permutation pi(q*8+j)=q*4+(j&3)+16*(j>>2) so C/D layout == next layer's B layout
// in-lane (HW-verified: absmax 0.0156). 2 experts/wave, 4 waves/tile (R8 = best measured).
// R13: R8 verbatim EXCEPT the cross-wave combine: LDS parity buffer + __syncthreads replaced
//     by atomicAdd of each wave's bpermute-pulled quad-partial onto memset-zeroed out.
//     4 commutative f32 adds per output word, no barrier, no LDS, no ordering assumption.
//     Everything else (fetch pattern, registers, gate, experts) byte-identical to R8.

typedef _Float16 half2_t __attribute__((ext_vector_type(2)));
typedef _Float16 half4_t __attribute__((ext_vector_type(4)));
typedef _Float16 half8_t __attribute__((ext_vector_type(8)));
typedef __fp16   fp16v2  __attribute__((ext_vector_type(2)));
typedef float  float4_t __attribute__((ext_vector_type(4)));
typedef float  float2_t __attribute__((ext_vector_type(2)));
typedef int    int2_t   __attribute__((ext_vector_type(2)));
typedef int    int4_t   __attribute__((ext_vector_type(4)));

#define MFMA_K32(A, B, C) __builtin_amdgcn_mfma_f32_16x16x32_f16((A), (B), (C), 0, 0, 0)
#define MFMA_K16(A, B, C) __builtin_amdgcn_mfma_f32_16x16x16f16((A), (B), (C), 0, 0, 0)

static constexpr int E_ = 8, DIN_ = 6, H_ = 32, EPW_ = 2;   // experts per wave

union H8U { half2_t h2[4]; half8_t h8; int4_t i4; };
union H4U { half2_t h2[2]; half4_t h4; int2_t i2; };
union HI  { half2_t h; int i; };
union PKU { fp16v2 p; half2_t h; };
union FI  { float f; int i; };

__device__ __forceinline__ half2_t pkrtz(float a, float b) {
    PKU u; u.p = __builtin_amdgcn_cvt_pkrtz(a, b);
    return u.h;
}

__device__ __forceinline__ half2_t relu2(half2_t v) {
    const half2_t z = {(_Float16)0.0f, (_Float16)0.0f};
    return __builtin_elementwise_max(v, z);
}

__device__ __forceinline__ float bperm_f(int addr, float v) {
    FI u; u.f = v;
    u.i = __builtin_amdgcn_ds_bpermute(addr, u.i);
    return u.f;
}

__global__ __launch_bounds__(256, 2)
void moe_kernel(
    const float* __restrict__ x,  const float* __restrict__ W1, const float* __restrict__ b1,
    const float* __restrict__ W2, const float* __restrict__ b2, const float* __restrict__ W3,
    const float* __restrict__ b3, const float* __restrict__ Wg1, const float* __restrict__ bg1,
    const float* __restrict__ Wg2, const float* __restrict__ bg2,
    float* __restrict__ out, int nTiles, int tilesPerBlock)
{
    const int tid  = threadIdx.x;
    const int lane = tid & 63;
    const int t    = lane & 15;   // token slot
    const int q    = lane >> 4;   // K-quad
    const int wv   = tid >> 6;    // wave in block: 0..3
    const int eb   = wv * EPW_;   // this wave's expert base

    const float L2E = 1.44269504f;

    // ---- gate L1 A-fragments (K=16, k=4q+j; slots 0..5 = x features, 6 = bias-as-1.0)
    H4U G1[2];
    #pragma unroll
    for (int f = 0; f < 2; ++f) {
        float v0 = 0.f, v1 = 0.f, v2 = 0.f, v3 = 0.f;
        if (q == 0) {
            v0 = Wg1[0 * H_ + f * 16 + t]; v1 = Wg1[1 * H_ + f * 16 + t];
            v2 = Wg1[2 * H_ + f * 16 + t]; v3 = Wg1[3 * H_ + f * 16 + t];
        } else if (q == 1) {
            v0 = Wg1[4 * H_ + f * 16 + t]; v1 = Wg1[5 * H_ + f * 16 + t];
            v2 = bg1[f * 16 + t];          v3 = 0.f;
        }
        G1[f].h2[0] = pkrtz(v0, v1); G1[f].h2[1] = pkrtz(v2, v3);
    }
    // ---- gate L2 A-fragment (K=32, pi layout), pre-scaled by log2(e)
    H8U G2;
    #pragma unroll
    for (int p = 0; p < 4; ++p) {
        int c0 = ((p >> 1) << 4) + q * 4 + ((p & 1) << 1);
        float v0 = (t < E_) ? Wg2[c0 * E_ + t] * L2E : 0.f;
        float v1 = (t < E_) ? Wg2[(c0 + 1) * E_ + t] * L2E : 0.f;
        G2.h2[p] = pkrtz(v0, v1);
    }

    // ---- this wave's 2 experts: L1 (K16), L2 (K32 pi), L3 (K32 pi, block-diag), b2 pairs
    H4U W1F[EPW_][2];
    H8U W2F[EPW_][2], W3F[EPW_], B2R[EPW_];
    #pragma unroll
    for (int j = 0; j < EPW_; ++j) {
        const int e = eb + j;
        #pragma unroll
        for (int f = 0; f < 2; ++f) {
            float v0 = 0.f, v1 = 0.f, v2 = 0.f, v3 = 0.f;
            const float* We = W1 + (size_t)e * DIN_ * H_ + f * 16 + t;
            if (q == 0)      { v0 = We[0 * H_]; v1 = We[1 * H_]; v2 = We[2 * H_]; v3 = We[3 * H_]; }
            else if (q == 1) { v0 = We[4 * H_]; v1 = We[5 * H_]; v2 = b1[e * H_ + f * 16 + t]; }
            W1F[j][f].h2[0] = pkrtz(v0, v1); W1F[j][f].h2[1] = pkrtz(v2, v3);
        }
        #pragma unroll
        for (int p = 0; p < 4; ++p) {
            int c0 = ((p >> 1) << 4) + q * 4 + ((p & 1) << 1);
            W2F[j][0].h2[p] = pkrtz(W2[(e * H_ + c0) * H_ + 0  + t], W2[(e * H_ + c0 + 1) * H_ + 0  + t]);
            W2F[j][1].h2[p] = pkrtz(W2[(e * H_ + c0) * H_ + 16 + t], W2[(e * H_ + c0 + 1) * H_ + 16 + t]);
            B2R[j].h2[p]    = pkrtz(b2[e * H_ + c0], b2[e * H_ + c0 + 1]);
            float v0 = 0.f, v1 = 0.f;
            if ((t >> 1) == e) {
                v0 = W3[(e * H_ + c0) * 2 + (t & 1)];
                v1 = W3[(e * H_ + c0 + 1) * 2 + (t & 1)];
            }
            W3F[j].h2[p] = pkrtz(v0, v1);
        }
    }

    // ---- persistent C-inits: bg2 (log2 domain); b3 rows m=4wv+r == this wave's (e,o) rows
    //      (quad-wv partial is the only one consumed, so b3 is counted exactly once)
    float4_t bg2F, b3F;
    #pragma unroll
    for (int r = 0; r < 4; ++r) {
        int m = q * 4 + r;
        bg2F[r] = (m < E_) ? bg2[m] * L2E : 0.f;
        b3F[r]  = b3[m];
    }
    const float4_t zero4 = {0.f, 0.f, 0.f, 0.f};

    const int gsrc = ((((q >> 1) << 4) | t) << 2);   // gate distribute pull
    const int csrc = (((wv << 4) | t) << 2);         // combine pull (quad wv)

    const int tile0 = blockIdx.x * tilesPerBlock;

    // per-lane x source offsets (quads>=2 values never consumed: A-frags zero at k>=8)
    const int xo1 = (q == 0) ? 0 : 4;
    const int xo2 = (q == 0) ? 2 : 4;
    const float* xq = x + ((size_t)tile0 * 16 + t) * DIN_;
    const int strideT = 16 * DIN_;

    float2_t la = {0.f, 0.f}, lb = {0.f, 0.f};
    if (tile0 < nTiles) {
        la = *(const float2_t*)(xq + xo1);
        lb = *(const float2_t*)(xq + xo2);
    }

    HI onei; onei.h = pkrtz(1.f, 0.f);
    const bool isq0 = (q == 0);

    // atomic slot: lanes 0-15 add out[tok*2], lanes 16-31 add out[tok*2+1]
    const int osel = (lane >> 4) & 1;

    for (int it = 0; it < tilesPerBlock; ++it) {
        const int tile = tile0 + it;
        if (tile >= nTiles) break;          // uniform across the block

        // ---- x B-fragment (K=16): q0:(x0..x3) q1:(x4,x5,1,dc) q2/q3: dc (A zero there)
        H4U ux;
        ux.h2[0] = pkrtz(la[0], la[1]);
        HI hb; hb.h = pkrtz(lb[0], lb[1]);
        HI se; se.i = isq0 ? hb.i : onei.i;
        ux.h2[1] = se.h;
        const half4_t xB = ux.h4;

        // ---- prefetch next tile's x
        if ((it + 1) < tilesPerBlock && (tile + 1) < nTiles) {
            const float* xn = xq + (size_t)(it + 1) * strideT;
            la = *(const float2_t*)(xn + xo1);
            lb = *(const float2_t*)(xn + xo2);
        }

        // ---- gate (each wave computes it; logits already in log2 domain)
        float4_t hgLo = MFMA_K16(G1[0].h4, xB, zero4);
        float4_t hgHi = MFMA_K16(G1[1].h4, xB, zero4);
        H8U uh;
        uh.h2[0] = relu2(pkrtz(hgLo[0], hgLo[1]));
        uh.h2[1] = relu2(pkrtz(hgLo[2], hgLo[3]));
        uh.h2[2] = relu2(pkrtz(hgHi[0], hgHi[1]));
        uh.h2[3] = relu2(pkrtz(hgHi[2], hgHi[3]));
        float4_t gl = MFMA_K32(G2.h8, uh.h8, bg2F);

        // ---- softmax over 8 experts, no max-sub (|logit| bounded), normalization deferred
        float ex0 = __builtin_amdgcn_exp2f(gl[0]);
        float ex1 = __builtin_amdgcn_exp2f(gl[1]);
        float ex2 = __builtin_amdgcn_exp2f(gl[2]);
        float ex3 = __builtin_amdgcn_exp2f(gl[3]);
        float s = (ex0 + ex1) + (ex2 + ex3);
        s += __shfl_xor(s, 16);
        float rs = __builtin_amdgcn_rcpf(s);   // valid in quads 0-1 (lanes 0-31)
        HI pa, pb;
        pa.h = pkrtz(ex0, ex1);
        pb.h = pkrtz(ex2, ex3);
        int va = __builtin_amdgcn_ds_bpermute(gsrc, pa.i);
        int vb = __builtin_amdgcn_ds_bpermute(gsrc, pb.i);
        HI gsel; gsel.i = (q & 1) ? vb : va;   // lane(q,t): ex[t,2q], ex[t,2q+1]
        float ga = (float)gsel.h[0];
        float gb = (float)gsel.h[1];

        // ---- this wave's 2 experts
        float4_t Y = b3F;
        #pragma unroll
        for (int j = 0; j < EPW_; ++j) {
            float4_t lo = MFMA_K16(W1F[j][0].h4, xB, zero4);
            float4_t hi = MFMA_K16(W1F[j][1].h4, xB, zero4);
            H8U u1;
            u1.h2[0] = relu2(pkrtz(lo[0], lo[1]));
            u1.h2[1] = relu2(pkrtz(lo[2], lo[3]));
            u1.h2[2] = relu2(pkrtz(hi[0], hi[1]));
            u1.h2[3] = relu2(pkrtz(hi[2], hi[3]));
            float4_t lo2 = MFMA_K32(W2F[j][0].h8, u1.h8, zero4);
            float4_t hi2 = MFMA_K32(W2F[j][1].h8, u1.h8, zero4);
            H8U u2;
            u2.h2[0] = relu2(pkrtz(lo2[0], lo2[1]) + B2R[j].h2[0]);
            u2.h2[1] = relu2(pkrtz(lo2[2], lo2[3]) + B2R[j].h2[1]);
            u2.h2[2] = relu2(pkrtz(hi2[0], hi2[1]) + B2R[j].h2[2]);
            u2.h2[3] = relu2(pkrtz(hi2[2], hi2[3]) + B2R[j].h2[3]);
            Y = MFMA_K32(W3F[j].h8, u2.h8, Y);
        }

        // ---- gated partial: only quad q==wv holds this wave's expert rows (m=4wv+r),
        //      complete incl. b3 and ex-weights. Pull it everywhere, normalize, atomic-add.
        float p0 = ga * Y[0] + gb * Y[2];
        float p1 = ga * Y[1] + gb * Y[3];
        p0 = bperm_f(csrc, p0);
        p1 = bperm_f(csrc, p1);
        if (lane < 32) {
            const int tok = tile * 16 + t;
            atomicAdd(out + (size_t)tok * 2 + osel, (osel ? p1 : p0) * rs);
        }
    }
}

extern "C" void kernel_launch(void* const* d_in, const int* in_sizes, int n_in,
                              void* d_out, int out_size, void* d_ws, size_t ws_size,
                              hipStream_t stream) {
    const float* x   = (const float*)d_in[0];
    const float* W1  = (const float*)d_in[1];
    const float* b1  = (const float*)d_in[2];
    const float* W2  = (const float*)d_in[3];
    const float* b2  = (const float*)d_in[4];
    const float* W3  = (const float*)d_in[5];
    const float* b3  = (const float*)d_in[6];
    const float* Wg1 = (const float*)d_in[7];
    const float* bg1 = (const float*)d_in[8];
    const float* Wg2 = (const float*)d_in[9];
    const float* bg2 = (const float*)d_in[10];
    float* out = (float*)d_out;

    const int B      = in_sizes[0] / DIN_;
    const int nTiles = (B + 15) / 16;
    const int blocks = 2048;                 // 32 tiles/block, exact at B=1M
    const int tpb    = (nTiles + blocks - 1) / blocks;

    hipMemsetAsync(out, 0, (size_t)out_size * sizeof(float), stream);
    moe_kernel<<<blocks, 256, 0, stream>>>(x, W1, b1, W2, b2, W3, b3,
                                           Wg1, bg1, Wg2, bg2, out, nTiles, tpb);
}